// Round 1
// baseline (388.888 us; speedup 1.0000x reference)
//
#include <hip/hip_runtime.h>

typedef __attribute__((ext_vector_type(4))) float f32x4;
typedef __attribute__((ext_vector_type(8))) __bf16 bf16x8;
typedef __attribute__((ext_vector_type(4))) __bf16 bf16x4;
typedef __attribute__((ext_vector_type(8))) unsigned short ushort8;

#define DEVI __device__ __forceinline__

static constexpr int QLEN = 2048, BSZ = 4, DM = 1024, NH = 16, DH = 64;
static constexpr int MROWS = QLEN * BSZ;       // 8192
static constexpr long OSZ  = (long)MROWS * DM; // 8388608 elements per output tensor
static constexpr float SCL2E = 0.125f * 1.4426950408889634f; // SCALE * log2(e)

DEVI void gload_lds16(const void* g, void* l) {
  __builtin_amdgcn_global_load_lds(
      (__attribute__((address_space(1))) void*)(size_t)g,
      (__attribute__((address_space(3))) void*)l, 16, 0, 0);
}

// ---------------------------------------------------------------- fp32->bf16
__global__ void k_f32_to_bf16(const float* __restrict__ in, __bf16* __restrict__ out, int n4) {
  int i = blockIdx.x * blockDim.x + threadIdx.x;
  int stride = gridDim.x * blockDim.x;
  for (; i < n4; i += stride) {
    const float4 v = ((const float4*)in)[i];
    bf16x4 o = { (__bf16)v.x, (__bf16)v.y, (__bf16)v.z, (__bf16)v.w };
    ((bf16x4*)out)[i] = o;
  }
}

// ------------------------------------------------- W (K x N) -> W^T (N x K) bf16
__global__ void k_wtrans(const float* __restrict__ W, __bf16* __restrict__ Wt) {
  __shared__ float tile[64][65];
  const int tk = blockIdx.x >> 4;
  const int tn = blockIdx.x & 15;
  const int t = threadIdx.x;
  const int r = t >> 4;
  const int c4 = (t & 15) << 2;
#pragma unroll
  for (int i = 0; i < 4; ++i) {
    const float4 v = *(const float4*)&W[(size_t)(tk * 64 + r + i * 16) * DM + tn * 64 + c4];
    tile[r + i * 16][c4 + 0] = v.x;
    tile[r + i * 16][c4 + 1] = v.y;
    tile[r + i * 16][c4 + 2] = v.z;
    tile[r + i * 16][c4 + 3] = v.w;
  }
  __syncthreads();
#pragma unroll
  for (int i = 0; i < 4; ++i) {
    const int n = r + i * 16;
    bf16x4 o = { (__bf16)tile[c4 + 0][n], (__bf16)tile[c4 + 1][n],
                 (__bf16)tile[c4 + 2][n], (__bf16)tile[c4 + 3][n] };
    *(bf16x4*)&Wt[(size_t)(tn * 64 + n) * DM + tk * 64 + c4] = o;
  }
}

// ---------------------------------------------------------------- GEMM
// C(M x 1024) = A(M x 1024,bf16) @ Bt(1024 x 1024,bf16)^T + bias, fp32 out (+opt bf16 dup).
// 128x128 tile, BK=64, 4 waves (2x2), 16x16x32 MFMA, global_load_lds w=16,
// XOR swizzle (row&7)<<4 on byte-col: inverse-swizzled source + swizzled read.
__global__ __launch_bounds__(256, 2) void k_gemm(
    const __bf16* __restrict__ A, const __bf16* __restrict__ Bt,
    const float* __restrict__ bias, float* __restrict__ Cf, __bf16* __restrict__ Cb) {
  constexpr int K = 1024, N = 1024;
  __shared__ alignas(16) char lds[32768];
  char* Alds = lds;
  char* Blds = lds + 16384;

  const int t = threadIdx.x;
  const int l = t & 63;
  const int w = t >> 6;
  const int bid = blockIdx.x;
  const int n0 = (bid & 7) * 128;
  const int m0 = (bid >> 3) * 128;
  const int wr = w >> 1, wc = w & 1;

  f32x4 acc[4][4];
#pragma unroll
  for (int i = 0; i < 4; ++i)
#pragma unroll
    for (int j = 0; j < 4; ++j) acc[i][j] = (f32x4){0.f, 0.f, 0.f, 0.f};

  // fragment LDS byte addresses (constant over kt)
  int a_addr[2][4], b_addr[2][4];
#pragma unroll
  for (int s = 0; s < 2; ++s)
#pragma unroll
    for (int f = 0; f < 4; ++f) {
      const int ca = s * 64 + ((l >> 4) << 4);
      const int ra = wr * 64 + f * 16 + (l & 15);
      a_addr[s][f] = ra * 128 + (ca ^ ((ra & 7) << 4));
      const int rb = wc * 64 + f * 16 + (l & 15);
      b_addr[s][f] = rb * 128 + (ca ^ ((rb & 7) << 4));
    }

  // staging: granule g = i*256+t of 16B; row = g>>3, col16 = (g&7) ^ (row&7)
  int g_row[4], g_col[4];
#pragma unroll
  for (int i = 0; i < 4; ++i) {
    const int g = i * 256 + t;
    g_row[i] = g >> 3;
    g_col[i] = ((g & 7) ^ (g_row[i] & 7)) * 8;  // element offset
  }

  for (int kt = 0; kt < K / 64; ++kt) {
#pragma unroll
    for (int i = 0; i < 4; ++i) {
      gload_lds16(A + (size_t)(m0 + g_row[i]) * K + kt * 64 + g_col[i],
                  Alds + (size_t)(i * 256 + t) * 16);
      gload_lds16(Bt + (size_t)(n0 + g_row[i]) * K + kt * 64 + g_col[i],
                  Blds + (size_t)(i * 256 + t) * 16);
    }
    __syncthreads();  // drains vmcnt -> tiles ready
#pragma unroll
    for (int s = 0; s < 2; ++s) {
      bf16x8 af[4], bfr[4];
#pragma unroll
      for (int f = 0; f < 4; ++f) {
        af[f]  = *(const bf16x8*)(Alds + a_addr[s][f]);
        bfr[f] = *(const bf16x8*)(Blds + b_addr[s][f]);
      }
#pragma unroll
      for (int mi = 0; mi < 4; ++mi)
#pragma unroll
        for (int ni = 0; ni < 4; ++ni)
          acc[mi][ni] = __builtin_amdgcn_mfma_f32_16x16x32_bf16(af[mi], bfr[ni], acc[mi][ni], 0, 0, 0);
    }
    __syncthreads();  // compute done before next overwrite
  }

  const int rowb = m0 + wr * 64 + ((l >> 4) << 2);
  const int colb = n0 + wc * 64 + (l & 15);
#pragma unroll
  for (int ni = 0; ni < 4; ++ni) {
    const float bv = bias[colb + ni * 16];
#pragma unroll
    for (int mi = 0; mi < 4; ++mi)
#pragma unroll
      for (int r = 0; r < 4; ++r) {
        const float v = acc[mi][ni][r] + bv;
        const size_t idx = (size_t)(rowb + mi * 16 + r) * N + colb + ni * 16;
        Cf[idx] = v;
        if (Cb) Cb[idx] = (__bf16)v;
      }
  }
}

// ---------------------------------------------------------------- RoPE (q,k) -> bf16
__global__ void k_rope(const float* __restrict__ qf, const float* __restrict__ kf,
                       const float* __restrict__ fc, const float* __restrict__ fs,
                       __bf16* __restrict__ qr, __bf16* __restrict__ kr) {
  const int i = blockIdx.x * blockDim.x + threadIdx.x;  // float4 index, exact grid
  const int m = i >> 8;       // row (s*4+b)
  const int cp2 = i & 255;    // float4 within row
  const int s = m >> 2;
  const int p2 = cp2 & 15;    // pair-pair within head
  const float2 c2 = *(const float2*)&fc[s * 32 + p2 * 2];
  const float2 s2 = *(const float2*)&fs[s * 32 + p2 * 2];
  const float4 q4 = ((const float4*)qf)[i];
  const float4 k4 = ((const float4*)kf)[i];
  bf16x4 qo = { (__bf16)(q4.x * c2.x - q4.y * s2.x), (__bf16)(q4.x * s2.x + q4.y * c2.x),
                (__bf16)(q4.z * c2.y - q4.w * s2.y), (__bf16)(q4.z * s2.y + q4.w * c2.y) };
  bf16x4 ko = { (__bf16)(k4.x * c2.x - k4.y * s2.x), (__bf16)(k4.x * s2.x + k4.y * c2.x),
                (__bf16)(k4.z * c2.y - k4.w * s2.y), (__bf16)(k4.z * s2.y + k4.w * c2.y) };
  ((bf16x4*)qr)[i] = qo;
  ((bf16x4*)kr)[i] = ko;
}

// ---------------------------------------------------------------- flash attention
// grid: bh(64) x qt(32); 256 threads = 4 waves x 16 q-rows; KV tile = 64 keys.
__global__ __launch_bounds__(256, 2) void k_flash(
    const __bf16* __restrict__ Q, const __bf16* __restrict__ Kr,
    const __bf16* __restrict__ V, __bf16* __restrict__ O) {
  __shared__ alignas(16) char lds[24576];
  char* Klds = lds;            // [64 keys][128B] swizzled
  char* VTlds = lds + 8192;    // [64 d][128B of j] swizzled
  char* Plds = lds + 16384;    // 4 waves x [16 rows][128B]

  const int t = threadIdx.x, l = t & 63, w = t >> 6;
  const int bid = blockIdx.x;
  const int qt = bid & 31;
  const int bh = bid >> 5;
  const int b = bh >> 4, h = bh & 15;
  char* Pw = Plds + w * 2048;

  // Q fragments held in registers for whole kernel
  const int qrow = qt * 64 + w * 16 + (l & 15);
  bf16x8 qfrag[2];
#pragma unroll
  for (int s = 0; s < 2; ++s)
    qfrag[s] = *(const bf16x8*)(Q + (size_t)(qrow * 4 + b) * DM + h * 64 + s * 32 + ((l >> 4) << 3));

  f32x4 oacc[4];
  float m_run[4], l_run[4];
#pragma unroll
  for (int r = 0; r < 4; ++r) { m_run[r] = -3.0e38f; l_run[r] = 0.f; }
#pragma unroll
  for (int nf = 0; nf < 4; ++nf) oacc[nf] = (f32x4){0.f, 0.f, 0.f, 0.f};

  const int vj0 = (t & 31) * 2;   // even key row
  const int vd0 = (t >> 5) * 8;   // d group

  for (int kt = 0; kt < QLEN / 64; ++kt) {
    // stage K via global_load_lds (swizzled source, linear dest)
#pragma unroll
    for (int i = 0; i < 2; ++i) {
      const int g = i * 256 + t;
      const int j = g >> 3;
      const int c16 = (g & 7) ^ (j & 7);
      gload_lds16(Kr + (size_t)((kt * 64 + j) * 4 + b) * DM + h * 64 + c16 * 8,
                  Klds + (size_t)g * 16);
    }
    // stage V transposed: VT[d][j], packed pairs along j, swizzled
    {
      const __bf16* vsrc = V + (size_t)((kt * 64 + vj0) * 4 + b) * DM + h * 64 + vd0;
      const ushort8 r0 = *(const ushort8*)vsrc;
      const ushort8 r1 = *(const ushort8*)(vsrc + 4 * DM);
#pragma unroll
      for (int e = 0; e < 8; ++e) {
        const unsigned pack = (unsigned)r0[e] | ((unsigned)r1[e] << 16);
        const int d = vd0 + e;
        const int addr = (d * 128 + vj0 * 2) ^ ((d & 7) << 4);
        *(unsigned*)(VTlds + addr) = pack;
      }
    }
    __syncthreads();

    // S = Q K^T (per wave: 16 q-rows x 64 keys)
    f32x4 sacc[4];
#pragma unroll
    for (int nf = 0; nf < 4; ++nf) sacc[nf] = (f32x4){0.f, 0.f, 0.f, 0.f};
#pragma unroll
    for (int s = 0; s < 2; ++s) {
      const int cb = s * 64 + ((l >> 4) << 4);
#pragma unroll
      for (int nf = 0; nf < 4; ++nf) {
        const int j = nf * 16 + (l & 15);
        const bf16x8 kfrag = *(const bf16x8*)(Klds + j * 128 + (cb ^ ((j & 7) << 4)));
        sacc[nf] = __builtin_amdgcn_mfma_f32_16x16x32_bf16(qfrag[s], kfrag, sacc[nf], 0, 0, 0);
      }
    }

    // online softmax (row r of lane = (l>>4)*4 + r)
    float rmax[4];
#pragma unroll
    for (int r = 0; r < 4; ++r)
      rmax[r] = fmaxf(fmaxf(sacc[0][r], sacc[1][r]), fmaxf(sacc[2][r], sacc[3][r]));
#pragma unroll
    for (int msk = 1; msk <= 8; msk <<= 1)
#pragma unroll
      for (int r = 0; r < 4; ++r) rmax[r] = fmaxf(rmax[r], __shfl_xor(rmax[r], msk));
    float alpha[4];
#pragma unroll
    for (int r = 0; r < 4; ++r) {
      const float mn = fmaxf(m_run[r], rmax[r]);
      alpha[r] = __builtin_exp2f((m_run[r] - mn) * SCL2E);
      m_run[r] = mn;
    }
    float rsum[4] = {0.f, 0.f, 0.f, 0.f};
#pragma unroll
    for (int nf = 0; nf < 4; ++nf)
#pragma unroll
      for (int r = 0; r < 4; ++r) {
        const float p = __builtin_exp2f((sacc[nf][r] - m_run[r]) * SCL2E);
        rsum[r] += p;
        const int prow = ((l >> 4) << 2) + r;
        const int pcb = (nf * 16 + (l & 15)) * 2;
        *(__bf16*)(Pw + prow * 128 + (pcb ^ ((prow & 7) << 4))) = (__bf16)p;
      }
#pragma unroll
    for (int msk = 1; msk <= 8; msk <<= 1)
#pragma unroll
      for (int r = 0; r < 4; ++r) rsum[r] += __shfl_xor(rsum[r], msk);
#pragma unroll
    for (int r = 0; r < 4; ++r) l_run[r] = l_run[r] * alpha[r] + rsum[r];
#pragma unroll
    for (int nf = 0; nf < 4; ++nf)
#pragma unroll
      for (int r = 0; r < 4; ++r) oacc[nf][r] *= alpha[r];

    // O += P V
#pragma unroll
    for (int ks = 0; ks < 2; ++ks) {
      const int cb = ks * 64 + ((l >> 4) << 4);
      const int pr = l & 15;
      const bf16x8 pf = *(const bf16x8*)(Pw + pr * 128 + (cb ^ ((pr & 7) << 4)));
#pragma unroll
      for (int nf = 0; nf < 4; ++nf) {
        const int d = nf * 16 + (l & 15);
        const bf16x8 vf = *(const bf16x8*)(VTlds + d * 128 + (cb ^ ((d & 7) << 4)));
        oacc[nf] = __builtin_amdgcn_mfma_f32_16x16x32_bf16(pf, vf, oacc[nf], 0, 0, 0);
      }
    }
    __syncthreads();  // protect K/VT from next-tile staging
  }

#pragma unroll
  for (int nf = 0; nf < 4; ++nf)
#pragma unroll
    for (int r = 0; r < 4; ++r) {
      const int row = qt * 64 + w * 16 + ((l >> 4) << 2) + r;
      const float v = oacc[nf][r] / l_run[r];
      O[(size_t)(row * 4 + b) * DM + h * 64 + nf * 16 + (l & 15)] = (__bf16)v;
    }
}

// ---------------------------------------------------------------- launch
extern "C" void kernel_launch(void* const* d_in, const int* in_sizes, int n_in,
                              void* d_out, int out_size, void* d_ws, size_t ws_size,
                              hipStream_t stream) {
  const float* x    = (const float*)d_in[0];
  const float* fcos = (const float*)d_in[1];
  const float* fsin = (const float*)d_in[2];
  const float* Wq   = (const float*)d_in[3];
  const float* bq   = (const float*)d_in[4];
  const float* Wk   = (const float*)d_in[5];
  const float* bk   = (const float*)d_in[6];
  const float* Wv   = (const float*)d_in[7];
  const float* bv   = (const float*)d_in[8];
  const float* Wo   = (const float*)d_in[9];
  const float* bo   = (const float*)d_in[10];

  float* out_o = (float*)d_out;           // also q-fp32 scratch until final GEMM
  float* out_k = out_o + OSZ;
  float* out_v = out_o + 2 * OSZ;

  char* ws = (char*)d_ws;
  __bf16* xb  = (__bf16*)(ws);                         // 16 MB
  __bf16* wqt = (__bf16*)(ws + 16777216);              // 2 MB each
  __bf16* wkt = (__bf16*)(ws + 18874368);
  __bf16* wvt = (__bf16*)(ws + 20971520);
  __bf16* wot = (__bf16*)(ws + 23068672);
  __bf16* qr  = (__bf16*)(ws + 25165824);              // 16 MB
  __bf16* kr  = (__bf16*)(ws + 41943040);              // 16 MB
  __bf16* vb  = (__bf16*)(ws + 58720256);              // 16 MB
  __bf16* ao  = (__bf16*)(ws + 75497472);              // 16 MB   (total 88 MB)

  k_f32_to_bf16<<<2048, 256, 0, stream>>>(x, xb, (int)(OSZ / 4));
  k_wtrans<<<256, 256, 0, stream>>>(Wq, wqt);
  k_wtrans<<<256, 256, 0, stream>>>(Wk, wkt);
  k_wtrans<<<256, 256, 0, stream>>>(Wv, wvt);
  k_wtrans<<<256, 256, 0, stream>>>(Wo, wot);

  k_gemm<<<512, 256, 0, stream>>>(xb, wqt, bq, out_o, (__bf16*)nullptr); // q fp32 -> o-region scratch
  k_gemm<<<512, 256, 0, stream>>>(xb, wkt, bk, out_k, (__bf16*)nullptr); // k fp32 -> output 1
  k_gemm<<<512, 256, 0, stream>>>(xb, wvt, bv, out_v, vb);               // v fp32 -> output 2 (+bf16 dup)

  k_rope<<<8192, 256, 0, stream>>>(out_o, out_k, fcos, fsin, qr, kr);

  k_flash<<<2048, 256, 0, stream>>>(qr, kr, vb, ao);

  k_gemm<<<512, 256, 0, stream>>>(ao, wot, bo, out_o, (__bf16*)nullptr); // final o
}

// Round 2
// 259.292 us; speedup vs baseline: 1.4998x; 1.4998x over previous
//
#include <hip/hip_runtime.h>

typedef __attribute__((ext_vector_type(4))) float f32x4;
typedef __attribute__((ext_vector_type(16))) float f32x16;
typedef __attribute__((ext_vector_type(8))) __bf16 bf16x8;
typedef __attribute__((ext_vector_type(4))) __bf16 bf16x4;
typedef __attribute__((ext_vector_type(2))) __bf16 bf16x2;
typedef __attribute__((ext_vector_type(8))) unsigned short ushort8;
typedef __attribute__((ext_vector_type(4))) unsigned int u32x4;

#define DEVI __device__ __forceinline__

static constexpr int QLEN = 2048, BSZ = 4, DM = 1024, NH = 16, DH = 64;
static constexpr int MROWS = QLEN * BSZ;       // 8192
static constexpr long OSZ  = (long)MROWS * DM; // 8388608 elements per output tensor
static constexpr float SCL2E = 0.125f * 1.4426950408889634f; // SCALE * log2(e)
static constexpr float RAW_THR = 4.0f / SCL2E;               // defer-max threshold (raw s units)

DEVI void gload_lds16(const void* g, void* l) {
  __builtin_amdgcn_global_load_lds(
      (__attribute__((address_space(1))) void*)(size_t)g,
      (__attribute__((address_space(3))) void*)l, 16, 0, 0);
}

DEVI f32x16 zero16() {
  f32x16 v;
#pragma unroll
  for (int i = 0; i < 16; ++i) v[i] = 0.f;
  return v;
}

DEVI unsigned pack_bf16(float lo, float hi) {
  bf16x2 v = { (__bf16)lo, (__bf16)hi };
  return __builtin_bit_cast(unsigned, v);
}

// ---------------------------------------------------------------- fp32->bf16
__global__ void k_f32_to_bf16(const float* __restrict__ in, __bf16* __restrict__ out, int n4) {
  int i = blockIdx.x * blockDim.x + threadIdx.x;
  int stride = gridDim.x * blockDim.x;
  for (; i < n4; i += stride) {
    const float4 v = ((const float4*)in)[i];
    bf16x4 o = { (__bf16)v.x, (__bf16)v.y, (__bf16)v.z, (__bf16)v.w };
    ((bf16x4*)out)[i] = o;
  }
}

// ------------------------------------------------- W (K x N) -> W^T (N x K) bf16
__global__ void k_wtrans(const float* __restrict__ W, __bf16* __restrict__ Wt) {
  __shared__ float tile[64][65];
  const int tk = blockIdx.x >> 4;
  const int tn = blockIdx.x & 15;
  const int t = threadIdx.x;
  const int r = t >> 4;
  const int c4 = (t & 15) << 2;
#pragma unroll
  for (int i = 0; i < 4; ++i) {
    const float4 v = *(const float4*)&W[(size_t)(tk * 64 + r + i * 16) * DM + tn * 64 + c4];
    tile[r + i * 16][c4 + 0] = v.x;
    tile[r + i * 16][c4 + 1] = v.y;
    tile[r + i * 16][c4 + 2] = v.z;
    tile[r + i * 16][c4 + 3] = v.w;
  }
  __syncthreads();
#pragma unroll
  for (int i = 0; i < 4; ++i) {
    const int n = r + i * 16;
    bf16x4 o = { (__bf16)tile[c4 + 0][n], (__bf16)tile[c4 + 1][n],
                 (__bf16)tile[c4 + 2][n], (__bf16)tile[c4 + 3][n] };
    *(bf16x4*)&Wt[(size_t)(tn * 64 + n) * DM + tk * 64 + c4] = o;
  }
}

// ---------------------------------------------------------------- GEMM
__global__ __launch_bounds__(256, 2) void k_gemm(
    const __bf16* __restrict__ A, const __bf16* __restrict__ Bt,
    const float* __restrict__ bias, float* __restrict__ Cf, __bf16* __restrict__ Cb) {
  constexpr int K = 1024, N = 1024;
  __shared__ alignas(16) char lds[32768];
  char* Alds = lds;
  char* Blds = lds + 16384;

  const int t = threadIdx.x;
  const int l = t & 63;
  const int w = t >> 6;
  const int bid = blockIdx.x;
  const int n0 = (bid & 7) * 128;
  const int m0 = (bid >> 3) * 128;
  const int wr = w >> 1, wc = w & 1;

  f32x4 acc[4][4];
#pragma unroll
  for (int i = 0; i < 4; ++i)
#pragma unroll
    for (int j = 0; j < 4; ++j) acc[i][j] = (f32x4){0.f, 0.f, 0.f, 0.f};

  int a_addr[2][4], b_addr[2][4];
#pragma unroll
  for (int s = 0; s < 2; ++s)
#pragma unroll
    for (int f = 0; f < 4; ++f) {
      const int ca = s * 64 + ((l >> 4) << 4);
      const int ra = wr * 64 + f * 16 + (l & 15);
      a_addr[s][f] = ra * 128 + (ca ^ ((ra & 7) << 4));
      const int rb = wc * 64 + f * 16 + (l & 15);
      b_addr[s][f] = rb * 128 + (ca ^ ((rb & 7) << 4));
    }

  int g_row[4], g_col[4];
#pragma unroll
  for (int i = 0; i < 4; ++i) {
    const int g = i * 256 + t;
    g_row[i] = g >> 3;
    g_col[i] = ((g & 7) ^ (g_row[i] & 7)) * 8;
  }

  for (int kt = 0; kt < K / 64; ++kt) {
#pragma unroll
    for (int i = 0; i < 4; ++i) {
      gload_lds16(A + (size_t)(m0 + g_row[i]) * K + kt * 64 + g_col[i],
                  Alds + (size_t)(i * 256 + t) * 16);
      gload_lds16(Bt + (size_t)(n0 + g_row[i]) * K + kt * 64 + g_col[i],
                  Blds + (size_t)(i * 256 + t) * 16);
    }
    __syncthreads();
#pragma unroll
    for (int s = 0; s < 2; ++s) {
      bf16x8 af[4], bfr[4];
#pragma unroll
      for (int f = 0; f < 4; ++f) {
        af[f]  = *(const bf16x8*)(Alds + a_addr[s][f]);
        bfr[f] = *(const bf16x8*)(Blds + b_addr[s][f]);
      }
#pragma unroll
      for (int mi = 0; mi < 4; ++mi)
#pragma unroll
        for (int ni = 0; ni < 4; ++ni)
          acc[mi][ni] = __builtin_amdgcn_mfma_f32_16x16x32_bf16(af[mi], bfr[ni], acc[mi][ni], 0, 0, 0);
    }
    __syncthreads();
  }

  const int rowb = m0 + wr * 64 + ((l >> 4) << 2);
  const int colb = n0 + wc * 64 + (l & 15);
#pragma unroll
  for (int ni = 0; ni < 4; ++ni) {
    const float bv = bias[colb + ni * 16];
#pragma unroll
    for (int mi = 0; mi < 4; ++mi)
#pragma unroll
      for (int r = 0; r < 4; ++r) {
        const float v = acc[mi][ni][r] + bv;
        const size_t idx = (size_t)(rowb + mi * 16 + r) * N + colb + ni * 16;
        Cf[idx] = v;
        if (Cb) Cb[idx] = (__bf16)v;
      }
  }
}

// ---------------------------------------------------------------- RoPE (q,k) -> bf16
__global__ void k_rope(const float* __restrict__ qf, const float* __restrict__ kf,
                       const float* __restrict__ fc, const float* __restrict__ fs,
                       __bf16* __restrict__ qr, __bf16* __restrict__ kr) {
  const int i = blockIdx.x * blockDim.x + threadIdx.x;
  const int m = i >> 8;
  const int cp2 = i & 255;
  const int s = m >> 2;
  const int p2 = cp2 & 15;
  const float2 c2 = *(const float2*)&fc[s * 32 + p2 * 2];
  const float2 s2 = *(const float2*)&fs[s * 32 + p2 * 2];
  const float4 q4 = ((const float4*)qf)[i];
  const float4 k4 = ((const float4*)kf)[i];
  bf16x4 qo = { (__bf16)(q4.x * c2.x - q4.y * s2.x), (__bf16)(q4.x * s2.x + q4.y * c2.x),
                (__bf16)(q4.z * c2.y - q4.w * s2.y), (__bf16)(q4.z * s2.y + q4.w * c2.y) };
  bf16x4 ko = { (__bf16)(k4.x * c2.x - k4.y * s2.x), (__bf16)(k4.x * s2.x + k4.y * c2.x),
                (__bf16)(k4.z * c2.y - k4.w * s2.y), (__bf16)(k4.z * s2.y + k4.w * c2.y) };
  ((bf16x4*)qr)[i] = qo;
  ((bf16x4*)kr)[i] = ko;
}

// ---------------------------------------------------------------- flash attention v2
// Swapped-operand 32x32x16 structure: grid = bh(64) x qt(16); 256 thr = 4 waves,
// each wave owns 32 q-rows. KV tile 64 keys, double-buffered LDS, 1 barrier/tile.
// S^T = mfma(K, Q^T): lane owns q = l&31; softmax in-register; P packed to bf16x2
// words, halves exchanged via shfl_xor(32); O^T = mfma(V^T, P^T).
__global__ __launch_bounds__(256, 4) void k_flash2(
    const __bf16* __restrict__ Q, const __bf16* __restrict__ Kr,
    const __bf16* __restrict__ V, __bf16* __restrict__ O) {
  __shared__ alignas(16) char lds[32768];  // 2 bufs x (K 8KB + VT 8KB)

  const int t = threadIdx.x, l = t & 63, w = t >> 6;
  const int hf = l >> 5;       // wave half
  const int q32 = l & 31;      // lane's q within wave tile
  const int bid = blockIdx.x;
  const int qt = bid & 15;
  const int bh = bid >> 4;
  const int b = bh >> 4, hd = bh & 15;

  const int qrow = qt * 128 + w * 32 + q32;

  // Q fragments: Q[q][d = kc*16 + hf*8 + e]
  bf16x8 qf[4];
#pragma unroll
  for (int kc = 0; kc < 4; ++kc)
    qf[kc] = *(const bf16x8*)(Q + (size_t)(qrow * 4 + b) * DM + hd * 64 + kc * 16 + hf * 8);

  f32x16 acc0 = zero16(), acc1 = zero16();
  float m_run = -3.0e38f, l_run = 0.f;

  // V reg-staging geometry: 2 key rows x 8 d per thread
  const int vj0 = (t & 31) * 2;
  const int vd0 = (t >> 5) * 8;

  // ---- prologue: stage tile 0 into buf 0
  {
    char* Kl = lds;
#pragma unroll
    for (int i = 0; i < 2; ++i) {
      const int g = i * 256 + t;
      const int j = g >> 3;
      const int c16 = (g & 7) ^ (j & 7);
      gload_lds16(Kr + (size_t)((0 * 64 + j) * 4 + b) * DM + hd * 64 + c16 * 8,
                  Kl + (size_t)g * 16);
    }
    const __bf16* vsrc = V + (size_t)((0 * 64 + vj0) * 4 + b) * DM + hd * 64 + vd0;
    const ushort8 r0 = *(const ushort8*)vsrc;
    const ushort8 r1 = *(const ushort8*)(vsrc + 4 * DM);
    char* Vl = lds + 8192;
#pragma unroll
    for (int e = 0; e < 8; ++e) {
      const unsigned pack = (unsigned)r0[e] | ((unsigned)r1[e] << 16);
      const int d = vd0 + e;
      const int addr = (d * 128 + vj0 * 2) ^ ((d & 7) << 4);
      *(unsigned*)(Vl + addr) = pack;
    }
  }

  for (int kt = 0; kt < QLEN / 64; ++kt) {
    const int cur = kt & 1;
    char* Kl = lds + cur * 16384;
    char* Vl = Kl + 8192;
    char* Kn = lds + (cur ^ 1) * 16384;
    char* Vn = Kn + 8192;

    __syncthreads();  // buf[cur] fully staged; buf[cur^1] free

    // ---- issue next-tile staging (T14: issue-early, write-late)
    ushort8 vr0, vr1;
    const bool have_next = (kt + 1) < QLEN / 64;
    if (have_next) {
#pragma unroll
      for (int i = 0; i < 2; ++i) {
        const int g = i * 256 + t;
        const int j = g >> 3;
        const int c16 = (g & 7) ^ (j & 7);
        gload_lds16(Kr + (size_t)(((kt + 1) * 64 + j) * 4 + b) * DM + hd * 64 + c16 * 8,
                    Kn + (size_t)g * 16);
      }
      const __bf16* vsrc = V + (size_t)(((kt + 1) * 64 + vj0) * 4 + b) * DM + hd * 64 + vd0;
      vr0 = *(const ushort8*)vsrc;
      vr1 = *(const ushort8*)(vsrc + 4 * DM);
    }

    // ---- two 32-key chunks
#pragma unroll
    for (int c = 0; c < 2; ++c) {
      // S^T = K x Q^T over d=64 (4 mfma)
      f32x16 sc = zero16();
#pragma unroll
      for (int kc = 0; kc < 4; ++kc) {
        const int j = c * 32 + q32;
        const bf16x8 kf = *(const bf16x8*)(Kl + j * 128 + ((kc * 32 + hf * 16) ^ ((j & 7) << 4)));
        sc = __builtin_amdgcn_mfma_f32_32x32x16_bf16(kf, qf[kc], sc, 0, 0, 0);
      }

      // row max over this chunk's 32 keys (in-lane tree + cross-half)
      float red[8];
#pragma unroll
      for (int i = 0; i < 8; ++i) red[i] = fmaxf(sc[i], sc[i + 8]);
#pragma unroll
      for (int i = 0; i < 4; ++i) red[i] = fmaxf(red[i], red[i + 4]);
      float pmax = fmaxf(fmaxf(red[0], red[2]), fmaxf(red[1], red[3]));
      pmax = fmaxf(pmax, __shfl_xor(pmax, 32));

      // defer-max rescale (T13)
      if (!__all(pmax - m_run <= RAW_THR)) {
        const float mn = fmaxf(m_run, pmax);
        const float alpha = __builtin_amdgcn_exp2f((m_run - mn) * SCL2E);
        l_run *= alpha;
        acc0 = acc0 * alpha;
        acc1 = acc1 * alpha;
        m_run = mn;
      }

      // p = exp2((s - m)*scale), in place; row sum
#pragma unroll
      for (int r = 0; r < 16; ++r) sc[r] = __builtin_amdgcn_exp2f((sc[r] - m_run) * SCL2E);
      float sred[8];
#pragma unroll
      for (int i = 0; i < 8; ++i) sred[i] = sc[i] + sc[i + 8];
#pragma unroll
      for (int i = 0; i < 4; ++i) sred[i] = sred[i] + sred[i + 4];
      float rs = (sred[0] + sred[2]) + (sred[1] + sred[3]);
      rs += __shfl_xor(rs, 32);
      l_run += rs;

      // pack p pairs: pk[m*2+i] = keys(8m + 4hf + 2i, +1)
      unsigned pk[8], yk[8];
#pragma unroll
      for (int m = 0; m < 4; ++m)
#pragma unroll
        for (int i = 0; i < 2; ++i)
          pk[m * 2 + i] = pack_bf16(sc[4 * m + 2 * i], sc[4 * m + 2 * i + 1]);
#pragma unroll
      for (int i = 0; i < 8; ++i) yk[i] = __shfl_xor((int)pk[i], 32);

      // PV: O^T += V^T P^T for the 2 j-chunks of this key chunk
#pragma unroll
      for (int jc2 = 0; jc2 < 2; ++jc2) {
        const unsigned a0 = pk[4 * jc2 + 0], a1 = pk[4 * jc2 + 1];
        const unsigned b0 = pk[4 * jc2 + 2], b1 = pk[4 * jc2 + 3];
        const unsigned ya0 = yk[4 * jc2 + 0], ya1 = yk[4 * jc2 + 1];
        const unsigned yb0 = yk[4 * jc2 + 2], yb1 = yk[4 * jc2 + 3];
        const u32x4 pw = { hf ? yb0 : a0, hf ? yb1 : a1, hf ? b0 : ya0, hf ? b1 : ya1 };
        const bf16x8 pf = __builtin_bit_cast(bf16x8, pw);
        const int jc = c * 2 + jc2;
        {
          const int dvt = 0 * 32 + q32;
          const bf16x8 vf = *(const bf16x8*)(Vl + dvt * 128 + ((jc * 32 + hf * 16) ^ ((dvt & 7) << 4)));
          acc0 = __builtin_amdgcn_mfma_f32_32x32x16_bf16(vf, pf, acc0, 0, 0, 0);
        }
        {
          const int dvt = 1 * 32 + q32;
          const bf16x8 vf = *(const bf16x8*)(Vl + dvt * 128 + ((jc * 32 + hf * 16) ^ ((dvt & 7) << 4)));
          acc1 = __builtin_amdgcn_mfma_f32_32x32x16_bf16(vf, pf, acc1, 0, 0, 0);
        }
      }
    }

    // ---- write-late: VT pack for next tile into buf[cur^1]
    if (have_next) {
#pragma unroll
      for (int e = 0; e < 8; ++e) {
        const unsigned pack = (unsigned)vr0[e] | ((unsigned)vr1[e] << 16);
        const int d = vd0 + e;
        const int addr = (d * 128 + vj0 * 2) ^ ((d & 7) << 4);
        *(unsigned*)(Vn + addr) = pack;
      }
    }
  }

  // ---- epilogue: O^T -> O, divide by l
  const float inv = 1.0f / l_run;
#pragma unroll
  for (int g = 0; g < 4; ++g) {
    {
      const int d0 = 0 * 32 + 8 * g + 4 * hf;
      bf16x4 o4 = { (__bf16)(acc0[4 * g + 0] * inv), (__bf16)(acc0[4 * g + 1] * inv),
                    (__bf16)(acc0[4 * g + 2] * inv), (__bf16)(acc0[4 * g + 3] * inv) };
      *(bf16x4*)&O[(size_t)(qrow * 4 + b) * DM + hd * 64 + d0] = o4;
    }
    {
      const int d0 = 1 * 32 + 8 * g + 4 * hf;
      bf16x4 o4 = { (__bf16)(acc1[4 * g + 0] * inv), (__bf16)(acc1[4 * g + 1] * inv),
                    (__bf16)(acc1[4 * g + 2] * inv), (__bf16)(acc1[4 * g + 3] * inv) };
      *(bf16x4*)&O[(size_t)(qrow * 4 + b) * DM + hd * 64 + d0] = o4;
    }
  }
}

// ---------------------------------------------------------------- launch
extern "C" void kernel_launch(void* const* d_in, const int* in_sizes, int n_in,
                              void* d_out, int out_size, void* d_ws, size_t ws_size,
                              hipStream_t stream) {
  const float* x    = (const float*)d_in[0];
  const float* fcos = (const float*)d_in[1];
  const float* fsin = (const float*)d_in[2];
  const float* Wq   = (const float*)d_in[3];
  const float* bq   = (const float*)d_in[4];
  const float* Wk   = (const float*)d_in[5];
  const float* bk   = (const float*)d_in[6];
  const float* Wv   = (const float*)d_in[7];
  const float* bv   = (const float*)d_in[8];
  const float* Wo   = (const float*)d_in[9];
  const float* bo   = (const float*)d_in[10];

  float* out_o = (float*)d_out;
  float* out_k = out_o + OSZ;
  float* out_v = out_o + 2 * OSZ;

  char* ws = (char*)d_ws;
  __bf16* xb  = (__bf16*)(ws);
  __bf16* wqt = (__bf16*)(ws + 16777216);
  __bf16* wkt = (__bf16*)(ws + 18874368);
  __bf16* wvt = (__bf16*)(ws + 20971520);
  __bf16* wot = (__bf16*)(ws + 23068672);
  __bf16* qr  = (__bf16*)(ws + 25165824);
  __bf16* kr  = (__bf16*)(ws + 41943040);
  __bf16* vb  = (__bf16*)(ws + 58720256);
  __bf16* ao  = (__bf16*)(ws + 75497472);

  k_f32_to_bf16<<<2048, 256, 0, stream>>>(x, xb, (int)(OSZ / 4));
  k_wtrans<<<256, 256, 0, stream>>>(Wq, wqt);
  k_wtrans<<<256, 256, 0, stream>>>(Wk, wkt);
  k_wtrans<<<256, 256, 0, stream>>>(Wv, wvt);
  k_wtrans<<<256, 256, 0, stream>>>(Wo, wot);

  k_gemm<<<512, 256, 0, stream>>>(xb, wqt, bq, out_o, (__bf16*)nullptr);
  k_gemm<<<512, 256, 0, stream>>>(xb, wkt, bk, out_k, (__bf16*)nullptr);
  k_gemm<<<512, 256, 0, stream>>>(xb, wvt, bv, out_v, vb);

  k_rope<<<8192, 256, 0, stream>>>(out_o, out_k, fcos, fsin, qr, kr);

  k_flash2<<<1024, 256, 0, stream>>>(qr, kr, vb, ao);

  k_gemm<<<512, 256, 0, stream>>>(ao, wot, bo, out_o, (__bf16*)nullptr);
}

// Round 3
// 226.757 us; speedup vs baseline: 1.7150x; 1.1435x over previous
//
#include <hip/hip_runtime.h>

typedef __attribute__((ext_vector_type(4))) float f32x4;
typedef __attribute__((ext_vector_type(16))) float f32x16;
typedef __attribute__((ext_vector_type(8))) __bf16 bf16x8;
typedef __attribute__((ext_vector_type(4))) __bf16 bf16x4;
typedef __attribute__((ext_vector_type(2))) __bf16 bf16x2;
typedef __attribute__((ext_vector_type(8))) unsigned short ushort8;
typedef __attribute__((ext_vector_type(4))) unsigned int u32x4;

#define DEVI __device__ __forceinline__

static constexpr int QLEN = 2048, BSZ = 4, DM = 1024, NH = 16, DH = 64;
static constexpr int MROWS = QLEN * BSZ;       // 8192
static constexpr long OSZ  = (long)MROWS * DM; // 8388608 elements per output tensor
static constexpr float SCL2E = 0.125f * 1.4426950408889634f; // SCALE * log2(e)
static constexpr float RAW_THR = 4.0f / SCL2E;               // defer-max threshold (raw s units)

DEVI void gload_lds16(const void* g, void* l) {
  __builtin_amdgcn_global_load_lds(
      (__attribute__((address_space(1))) void*)(size_t)g,
      (__attribute__((address_space(3))) void*)l, 16, 0, 0);
}

DEVI f32x16 zero16() {
  f32x16 v;
#pragma unroll
  for (int i = 0; i < 16; ++i) v[i] = 0.f;
  return v;
}

DEVI unsigned pack_bf16(float lo, float hi) {
  bf16x2 v = { (__bf16)lo, (__bf16)hi };
  return __builtin_bit_cast(unsigned, v);
}

// ---------------------------------------------------------------- fp32->bf16
__global__ void k_f32_to_bf16(const float* __restrict__ in, __bf16* __restrict__ out, int n4) {
  int i = blockIdx.x * blockDim.x + threadIdx.x;
  int stride = gridDim.x * blockDim.x;
  for (; i < n4; i += stride) {
    const float4 v = ((const float4*)in)[i];
    bf16x4 o = { (__bf16)v.x, (__bf16)v.y, (__bf16)v.z, (__bf16)v.w };
    ((bf16x4*)out)[i] = o;
  }
}

// ------------------------------------------------- W (K x N) -> W^T (N x K) bf16
__global__ void k_wtrans(const float* __restrict__ W, __bf16* __restrict__ Wt) {
  __shared__ float tile[64][65];
  const int tk = blockIdx.x >> 4;
  const int tn = blockIdx.x & 15;
  const int t = threadIdx.x;
  const int r = t >> 4;
  const int c4 = (t & 15) << 2;
#pragma unroll
  for (int i = 0; i < 4; ++i) {
    const float4 v = *(const float4*)&W[(size_t)(tk * 64 + r + i * 16) * DM + tn * 64 + c4];
    tile[r + i * 16][c4 + 0] = v.x;
    tile[r + i * 16][c4 + 1] = v.y;
    tile[r + i * 16][c4 + 2] = v.z;
    tile[r + i * 16][c4 + 3] = v.w;
  }
  __syncthreads();
#pragma unroll
  for (int i = 0; i < 4; ++i) {
    const int n = r + i * 16;
    bf16x4 o = { (__bf16)tile[c4 + 0][n], (__bf16)tile[c4 + 1][n],
                 (__bf16)tile[c4 + 2][n], (__bf16)tile[c4 + 3][n] };
    *(bf16x4*)&Wt[(size_t)(tn * 64 + n) * DM + tk * 64 + c4] = o;
  }
}

// ---------------------------------------------------------------- GEMM core (shared by both GEMMs)
// Computes one 128x128 tile of A(MxK) @ Bt(NxK)^T; acc in registers.
// Staging + MFMA identical to the verified round-2 kernel.
DEVI void gemm_tile_core(const __bf16* __restrict__ A, const __bf16* __restrict__ Bt,
                         char* Alds, char* Blds, int m0, int n0, int t,
                         f32x4 (&acc)[4][4]) {
  constexpr int K = 1024;
  const int l = t & 63;
  const int w = t >> 6;
  const int wr = w >> 1, wc = w & 1;

  int a_addr[2][4], b_addr[2][4];
#pragma unroll
  for (int s = 0; s < 2; ++s)
#pragma unroll
    for (int f = 0; f < 4; ++f) {
      const int ca = s * 64 + ((l >> 4) << 4);
      const int ra = wr * 64 + f * 16 + (l & 15);
      a_addr[s][f] = ra * 128 + (ca ^ ((ra & 7) << 4));
      const int rb = wc * 64 + f * 16 + (l & 15);
      b_addr[s][f] = rb * 128 + (ca ^ ((rb & 7) << 4));
    }

  int g_row[4], g_col[4];
#pragma unroll
  for (int i = 0; i < 4; ++i) {
    const int g = i * 256 + t;
    g_row[i] = g >> 3;
    g_col[i] = ((g & 7) ^ (g_row[i] & 7)) * 8;
  }

  for (int kt = 0; kt < K / 64; ++kt) {
#pragma unroll
    for (int i = 0; i < 4; ++i) {
      gload_lds16(A + (size_t)(m0 + g_row[i]) * K + kt * 64 + g_col[i],
                  Alds + (size_t)(i * 256 + t) * 16);
      gload_lds16(Bt + (size_t)(n0 + g_row[i]) * K + kt * 64 + g_col[i],
                  Blds + (size_t)(i * 256 + t) * 16);
    }
    __syncthreads();
#pragma unroll
    for (int s = 0; s < 2; ++s) {
      bf16x8 af[4], bfr[4];
#pragma unroll
      for (int f = 0; f < 4; ++f) {
        af[f]  = *(const bf16x8*)(Alds + a_addr[s][f]);
        bfr[f] = *(const bf16x8*)(Blds + b_addr[s][f]);
      }
#pragma unroll
      for (int mi = 0; mi < 4; ++mi)
#pragma unroll
        for (int ni = 0; ni < 4; ++ni)
          acc[mi][ni] = __builtin_amdgcn_mfma_f32_16x16x32_bf16(af[mi], bfr[ni], acc[mi][ni], 0, 0, 0);
    }
    __syncthreads();
  }
}

// Final GEMM: N=1024 single output
__global__ __launch_bounds__(256, 2) void k_gemm(
    const __bf16* __restrict__ A, const __bf16* __restrict__ Bt,
    const float* __restrict__ bias, float* __restrict__ Cf, __bf16* __restrict__ Cb) {
  __shared__ alignas(16) char lds[32768];
  const int t = threadIdx.x;
  const int l = t & 63;
  const int w = t >> 6;
  const int n0 = (blockIdx.x & 7) * 128;
  const int m0 = (blockIdx.x >> 3) * 128;
  const int wr = w >> 1, wc = w & 1;

  f32x4 acc[4][4];
#pragma unroll
  for (int i = 0; i < 4; ++i)
#pragma unroll
    for (int j = 0; j < 4; ++j) acc[i][j] = (f32x4){0.f, 0.f, 0.f, 0.f};

  gemm_tile_core(A, Bt, lds, lds + 16384, m0, n0, t, acc);

  const int rowb = m0 + wr * 64 + ((l >> 4) << 2);
  const int colb = n0 + wc * 64 + (l & 15);
#pragma unroll
  for (int ni = 0; ni < 4; ++ni) {
    const float bv = bias[colb + ni * 16];
#pragma unroll
    for (int mi = 0; mi < 4; ++mi)
#pragma unroll
      for (int r = 0; r < 4; ++r) {
        const float v = acc[mi][ni][r] + bv;
        const size_t idx = (size_t)(rowb + mi * 16 + r) * 1024 + colb + ni * 16;
        Cf[idx] = v;
        if (Cb) Cb[idx] = (__bf16)v;
      }
  }
}

// Fused QKV GEMM: Bt = [3072][1024] (Wq^T|Wk^T|Wv^T contiguous); per-block group routes
// bias/output. grid = 64 m-tiles x 24 n-tiles = 1536 blocks (6/CU).
__global__ __launch_bounds__(256, 2) void k_gemm_qkv(
    const __bf16* __restrict__ A, const __bf16* __restrict__ Bt,
    const float* __restrict__ bq, const float* __restrict__ bk, const float* __restrict__ bv,
    float* __restrict__ oq, float* __restrict__ ok, float* __restrict__ ov,
    __bf16* __restrict__ vb) {
  __shared__ alignas(16) char lds[32768];
  const int t = threadIdx.x;
  const int l = t & 63;
  const int w = t >> 6;
  const int nt = blockIdx.x % 24;
  const int n0 = nt * 128;
  const int m0 = (blockIdx.x / 24) * 128;
  const int wr = w >> 1, wc = w & 1;

  f32x4 acc[4][4];
#pragma unroll
  for (int i = 0; i < 4; ++i)
#pragma unroll
    for (int j = 0; j < 4; ++j) acc[i][j] = (f32x4){0.f, 0.f, 0.f, 0.f};

  gemm_tile_core(A, Bt, lds, lds + 16384, m0, n0, t, acc);

  const int grp = n0 >> 10;  // 0=q 1=k 2=v (block-uniform)
  const float* bias = grp == 0 ? bq : (grp == 1 ? bk : bv);
  float* Cf = grp == 0 ? oq : (grp == 1 ? ok : ov);
  __bf16* Cb = grp == 2 ? vb : nullptr;

  const int rowb = m0 + wr * 64 + ((l >> 4) << 2);
  const int colb = (n0 & 1023) + wc * 64 + (l & 15);
#pragma unroll
  for (int ni = 0; ni < 4; ++ni) {
    const float bvv = bias[colb + ni * 16];
#pragma unroll
    for (int mi = 0; mi < 4; ++mi)
#pragma unroll
      for (int r = 0; r < 4; ++r) {
        const float v = acc[mi][ni][r] + bvv;
        const size_t idx = (size_t)(rowb + mi * 16 + r) * 1024 + colb + ni * 16;
        Cf[idx] = v;
        if (Cb) Cb[idx] = (__bf16)v;
      }
  }
}

// ---------------------------------------------------------------- RoPE (q,k) -> bf16
__global__ void k_rope(const float* __restrict__ qf, const float* __restrict__ kf,
                       const float* __restrict__ fc, const float* __restrict__ fs,
                       __bf16* __restrict__ qr, __bf16* __restrict__ kr) {
  const int i = blockIdx.x * blockDim.x + threadIdx.x;
  const int m = i >> 8;
  const int cp2 = i & 255;
  const int s = m >> 2;
  const int p2 = cp2 & 15;
  const float2 c2 = *(const float2*)&fc[s * 32 + p2 * 2];
  const float2 s2 = *(const float2*)&fs[s * 32 + p2 * 2];
  const float4 q4 = ((const float4*)qf)[i];
  const float4 k4 = ((const float4*)kf)[i];
  bf16x4 qo = { (__bf16)(q4.x * c2.x - q4.y * s2.x), (__bf16)(q4.x * s2.x + q4.y * c2.x),
                (__bf16)(q4.z * c2.y - q4.w * s2.y), (__bf16)(q4.z * s2.y + q4.w * c2.y) };
  bf16x4 ko = { (__bf16)(k4.x * c2.x - k4.y * s2.x), (__bf16)(k4.x * s2.x + k4.y * c2.x),
                (__bf16)(k4.z * c2.y - k4.w * s2.y), (__bf16)(k4.z * s2.y + k4.w * c2.y) };
  ((bf16x4*)qr)[i] = qo;
  ((bf16x4*)kr)[i] = ko;
}

// ---------------------------------------------------------------- flash attention v3
// Fragment-major LDS: K and VT stored as 8 contiguous 1KB fragment slabs each
// (lane l's 16B at slab + l*16) -> all ds_read_b128 are contiguous 1KB wave reads
// (zero bank conflicts, immediate-offset addressing).
// K slab fi = c*4+kc holds K[j=c*32+(l&31)][d = kc*16+(l>>5)*8 ..+8].
// VT slab fi = jc*2+dh (stride 1040B, pad kills write conflicts) holds
// V[j=jc*16+(l>>5)*8 ..+8][d = dh*32+(l&31)].
// P cross-half exchange via v_permlane32_swap_b32 (replaces 8 bpermute + 8 cndmask).
static constexpr int KSLAB = 8192;          // 8 x 1024
static constexpr int VSLAB_STRIDE = 1040;   // 1024 + 16 pad
static constexpr int VSLAB = 8 * VSLAB_STRIDE;  // 8320
static constexpr int FBUF = KSLAB + VSLAB;      // 16512 per buffer

__global__ __launch_bounds__(256, 4) void k_flash3(
    const __bf16* __restrict__ Q, const __bf16* __restrict__ Kr,
    const __bf16* __restrict__ V, __bf16* __restrict__ O) {
  __shared__ alignas(16) char lds[2 * FBUF];

  const int t = threadIdx.x, l = t & 63, w = t >> 6;
  const int hf = l >> 5;
  const int q32 = l & 31;
  const int bid = blockIdx.x;
  const int qt = bid & 15;
  const int bh = bid >> 4;
  const int b = bh >> 4, hd = bh & 15;

  const int qrow = qt * 128 + w * 32 + q32;

  bf16x8 qf[4];
#pragma unroll
  for (int kc = 0; kc < 4; ++kc)
    qf[kc] = *(const bf16x8*)(Q + (size_t)(qrow * 4 + b) * DM + hd * 64 + kc * 16 + hf * 8);

  f32x16 acc0 = zero16(), acc1 = zero16();
  float m_run = -3.0e38f, l_run = 0.f;

  // K staging source geometry (per i in {0,1}): row j = i*32 + (t&31), dslice = (t>>5)*8
  const int ksrc_j = t & 31;
  const int ksrc_d = (t >> 5) * 8;

  // V reg-staging geometry: 2 key rows x 8 d per thread
  const int vj0 = (t & 31) * 2;
  const int vd0 = (t >> 5) * 8;
  // VT write base (fragment-major): fi = ((t&31)>>3)*2 + (t>>7);
  // lane slot l' = (((t&31)>>2)&1)*32 + (vd0&31) + e; dword = (t&31)&3
  const int vt_wbase = ((((t & 31) >> 3) * 2 + (t >> 7)) * VSLAB_STRIDE)
                     + (((((t & 31) >> 2) & 1) * 32 + (((t >> 5) & 3) * 8)) * 16)
                     + (((t & 31) & 3) * 4);

  // ---- prologue: stage tile 0 into buf 0
  {
    char* Kl = lds;
#pragma unroll
    for (int i = 0; i < 2; ++i)
      gload_lds16(Kr + (size_t)(((0 * 64) + i * 32 + ksrc_j) * 4 + b) * DM + hd * 64 + ksrc_d,
                  Kl + (size_t)(i * 256 + t) * 16);
    const __bf16* vsrc = V + (size_t)((0 * 64 + vj0) * 4 + b) * DM + hd * 64 + vd0;
    const ushort8 r0 = *(const ushort8*)vsrc;
    const ushort8 r1 = *(const ushort8*)(vsrc + 4 * DM);
    char* Vl = lds + KSLAB;
#pragma unroll
    for (int e = 0; e < 8; ++e) {
      const unsigned pack = (unsigned)r0[e] | ((unsigned)r1[e] << 16);
      *(unsigned*)(Vl + vt_wbase + e * 16) = pack;
    }
  }

  for (int kt = 0; kt < QLEN / 64; ++kt) {
    const int cur = kt & 1;
    char* Kl = lds + cur * FBUF;
    char* Vl = Kl + KSLAB;
    char* Kn = lds + (cur ^ 1) * FBUF;
    char* Vn = Kn + KSLAB;

    __syncthreads();  // buf[cur] staged; buf[cur^1] free

    // ---- issue next-tile staging (T14)
    ushort8 vr0, vr1;
    const bool have_next = (kt + 1) < QLEN / 64;
    if (have_next) {
#pragma unroll
      for (int i = 0; i < 2; ++i)
        gload_lds16(Kr + (size_t)((((kt + 1) * 64) + i * 32 + ksrc_j) * 4 + b) * DM + hd * 64 + ksrc_d,
                    Kn + (size_t)(i * 256 + t) * 16);
      const __bf16* vsrc = V + (size_t)(((kt + 1) * 64 + vj0) * 4 + b) * DM + hd * 64 + vd0;
      vr0 = *(const ushort8*)vsrc;
      vr1 = *(const ushort8*)(vsrc + 4 * DM);
    }

    // ---- two 32-key chunks
#pragma unroll
    for (int c = 0; c < 2; ++c) {
      f32x16 sc = zero16();
#pragma unroll
      for (int kc = 0; kc < 4; ++kc) {
        const bf16x8 kf = *(const bf16x8*)(Kl + (c * 4 + kc) * 1024 + l * 16);
        sc = __builtin_amdgcn_mfma_f32_32x32x16_bf16(kf, qf[kc], sc, 0, 0, 0);
      }

      float red[8];
#pragma unroll
      for (int i = 0; i < 8; ++i) red[i] = fmaxf(sc[i], sc[i + 8]);
#pragma unroll
      for (int i = 0; i < 4; ++i) red[i] = fmaxf(red[i], red[i + 4]);
      float pmax = fmaxf(fmaxf(red[0], red[2]), fmaxf(red[1], red[3]));
      pmax = fmaxf(pmax, __shfl_xor(pmax, 32));

      if (!__all(pmax - m_run <= RAW_THR)) {
        const float mn = fmaxf(m_run, pmax);
        const float alpha = __builtin_amdgcn_exp2f((m_run - mn) * SCL2E);
        l_run *= alpha;
        acc0 = acc0 * alpha;
        acc1 = acc1 * alpha;
        m_run = mn;
      }

#pragma unroll
      for (int r = 0; r < 16; ++r) sc[r] = __builtin_amdgcn_exp2f((sc[r] - m_run) * SCL2E);
      float sred[8];
#pragma unroll
      for (int i = 0; i < 8; ++i) sred[i] = sc[i] + sc[i + 8];
#pragma unroll
      for (int i = 0; i < 4; ++i) sred[i] = sred[i] + sred[i + 4];
      float rs = (sred[0] + sred[2]) + (sred[1] + sred[3]);
      rs += __shfl_xor(rs, 32);
      l_run += rs;

      unsigned pk[8];
#pragma unroll
      for (int m = 0; m < 4; ++m)
#pragma unroll
        for (int i = 0; i < 2; ++i)
          pk[m * 2 + i] = pack_bf16(sc[4 * m + 2 * i], sc[4 * m + 2 * i + 1]);

#pragma unroll
      for (int jc2 = 0; jc2 < 2; ++jc2) {
        // cross-half exchange: after swap, w0=[a.lo,b.lo] (words 0/1), w2=[a.hi,b.hi] (words 2/3)
        unsigned w0 = pk[4 * jc2 + 0], w2 = pk[4 * jc2 + 2];
        unsigned w1 = pk[4 * jc2 + 1], w3 = pk[4 * jc2 + 3];
        asm("v_permlane32_swap_b32 %0, %1" : "+v"(w0), "+v"(w2));
        asm("v_permlane32_swap_b32 %0, %1" : "+v"(w1), "+v"(w3));
        const u32x4 pw = { w0, w1, w2, w3 };
        const bf16x8 pf = __builtin_bit_cast(bf16x8, pw);
        const int jc = c * 2 + jc2;
        {
          const bf16x8 vf = *(const bf16x8*)(Vl + (jc * 2 + 0) * VSLAB_STRIDE + l * 16);
          acc0 = __builtin_amdgcn_mfma_f32_32x32x16_bf16(vf, pf, acc0, 0, 0, 0);
        }
        {
          const bf16x8 vf = *(const bf16x8*)(Vl + (jc * 2 + 1) * VSLAB_STRIDE + l * 16);
          acc1 = __builtin_amdgcn_mfma_f32_32x32x16_bf16(vf, pf, acc1, 0, 0, 0);
        }
      }
    }

    // ---- write-late: VT pack for next tile into buf[cur^1]
    if (have_next) {
#pragma unroll
      for (int e = 0; e < 8; ++e) {
        const unsigned pack = (unsigned)vr0[e] | ((unsigned)vr1[e] << 16);
        *(unsigned*)(Vn + vt_wbase + e * 16) = pack;
      }
    }
  }

  // ---- epilogue
  const float inv = 1.0f / l_run;
#pragma unroll
  for (int g = 0; g < 4; ++g) {
    {
      const int d0 = 0 * 32 + 8 * g + 4 * hf;
      bf16x4 o4 = { (__bf16)(acc0[4 * g + 0] * inv), (__bf16)(acc0[4 * g + 1] * inv),
                    (__bf16)(acc0[4 * g + 2] * inv), (__bf16)(acc0[4 * g + 3] * inv) };
      *(bf16x4*)&O[(size_t)(qrow * 4 + b) * DM + hd * 64 + d0] = o4;
    }
    {
      const int d0 = 1 * 32 + 8 * g + 4 * hf;
      bf16x4 o4 = { (__bf16)(acc1[4 * g + 0] * inv), (__bf16)(acc1[4 * g + 1] * inv),
                    (__bf16)(acc1[4 * g + 2] * inv), (__bf16)(acc1[4 * g + 3] * inv) };
      *(bf16x4*)&O[(size_t)(qrow * 4 + b) * DM + hd * 64 + d0] = o4;
    }
  }
}

// ---------------------------------------------------------------- launch
extern "C" void kernel_launch(void* const* d_in, const int* in_sizes, int n_in,
                              void* d_out, int out_size, void* d_ws, size_t ws_size,
                              hipStream_t stream) {
  const float* x    = (const float*)d_in[0];
  const float* fcos = (const float*)d_in[1];
  const float* fsin = (const float*)d_in[2];
  const float* Wq   = (const float*)d_in[3];
  const float* bq   = (const float*)d_in[4];
  const float* Wk   = (const float*)d_in[5];
  const float* bk   = (const float*)d_in[6];
  const float* Wv   = (const float*)d_in[7];
  const float* bv   = (const float*)d_in[8];
  const float* Wo   = (const float*)d_in[9];
  const float* bo   = (const float*)d_in[10];

  float* out_o = (float*)d_out;
  float* out_k = out_o + OSZ;
  float* out_v = out_o + 2 * OSZ;

  char* ws = (char*)d_ws;
  __bf16* xb  = (__bf16*)(ws);
  __bf16* wqt = (__bf16*)(ws + 16777216);  // wqt|wkt|wvt contiguous = [3072][1024]
  __bf16* wkt = (__bf16*)(ws + 18874368);
  __bf16* wvt = (__bf16*)(ws + 20971520);
  __bf16* wot = (__bf16*)(ws + 23068672);
  __bf16* qr  = (__bf16*)(ws + 25165824);
  __bf16* kr  = (__bf16*)(ws + 41943040);
  __bf16* vb  = (__bf16*)(ws + 58720256);
  __bf16* ao  = (__bf16*)(ws + 75497472);

  k_f32_to_bf16<<<2048, 256, 0, stream>>>(x, xb, (int)(OSZ / 4));
  k_wtrans<<<256, 256, 0, stream>>>(Wq, wqt);
  k_wtrans<<<256, 256, 0, stream>>>(Wk, wkt);
  k_wtrans<<<256, 256, 0, stream>>>(Wv, wvt);
  k_wtrans<<<256, 256, 0, stream>>>(Wo, wot);

  k_gemm_qkv<<<1536, 256, 0, stream>>>(xb, wqt, bq, bk, bv, out_o, out_k, out_v, vb);

  k_rope<<<8192, 256, 0, stream>>>(out_o, out_k, fcos, fsin, qr, kr);

  k_flash3<<<1024, 256, 0, stream>>>(qr, kr, vb, ao);

  k_gemm<<<512, 256, 0, stream>>>(ao, wot, bo, out_o, (__bf16*)nullptr);
}